// Round 7
// baseline (215.891 us; speedup 1.0000x reference)
//
#include <hip/hip_runtime.h>
#include <hip/hip_bf16.h>

// HorizonTemporalSelfAttention: multi-scale deformable attention
// bs=2, nq=16384, E=256, NH=8, NL=4, NP=4, d=32, total tokens=21760
//
// R7: logits stored as per-(b,h,q) 48-half records [32 off | 16 attn].
// R8: XCD-aware sampler swizzle (FETCH 126->43 MB; taps L2-resident).
// R9 (REVERTED): 1-thread-per-query broke intra-line coalescing (4x L2
//     transactions, 239 us). Lesson: keep 4 lanes x 16B = one 64B segment
//     per tap in ONE instruction.
// R12/R13: 1-deep / 4-deep named-buffer pipelines: allocator sank the loads
//     both times (VGPR stuck at 52); only ~4% each. Lesson: stop fighting
//     the scheduler; get latency hiding from TLP instead.
// R14: level-split. Thread = (query, level, c4): 4 points/thread, block =
//     16 q x 4 l x 4 c4, grid 16384 (XCD pinning kept). 4x waves, 4x
//     shorter dependency chains; quad coalescing unchanged. Cross-level
//     reduce in LDS, summed in level order (numerics identical).

typedef __attribute__((ext_vector_type(4))) float    float4v;
typedef __attribute__((ext_vector_type(8))) _Float16 half8;
typedef __attribute__((ext_vector_type(4))) _Float16 half4;
typedef __attribute__((ext_vector_type(2))) _Float16 half2v;

#define NQ    16384
#define NTOK  21760
#define LREC  48          // halves per (b,h,q) logit record: 32 off + 16 attn

#define GEMM_BLOCKS 768   // 256 M-tiles x 3 N-tiles
#define CONV_BLOCKS 10880 // 2785280 float4 / 256

union H8 { half8 v; half2v p[4]; };

// ---------------- K-F: fused GEMM + value convert ----------------
#define LDSTR 88
__global__ __launch_bounds__(256) void fused_kernel(
    const float* __restrict__ qf,
    const float* __restrict__ Woff, const float* __restrict__ Wattn,
    const float* __restrict__ boff, const float* __restrict__ battn,
    const float* __restrict__ val,
    _Float16* __restrict__ lh, _Float16* __restrict__ vh) {
  const int tid = threadIdx.x;

  if (blockIdx.x >= GEMM_BLOCKS) {
    // ---- value convert: f32 -> f16, one float4 per thread ----
    int i = (blockIdx.x - GEMM_BLOCKS) * 256 + tid;
    float4v v = ((const float4v*)val)[i];
    half4 o;
    o[0] = (_Float16)v[0]; o[1] = (_Float16)v[1];
    o[2] = (_Float16)v[2]; o[3] = (_Float16)v[3];
    ((half4*)vh)[i] = o;
    return;
  }

  // ---- GEMM: logits = q @ Wcat^T + bias -> per-(b,h,q) records ----
  __shared__ _Float16 As[128 * LDSTR];
  __shared__ _Float16 Bs[128 * LDSTR];

  const int lane = tid & 63;
  const int wv   = tid >> 6;
  const int wm   = wv >> 1, wn = wv & 1;
  const int quad = lane >> 4;
  const int r    = lane & 15;
  const int blockM = (blockIdx.x & 255) * 128;
  const int n0     = (blockIdx.x >> 8) * 128;

  float4v acc[4][4];
#pragma unroll
  for (int i = 0; i < 4; ++i)
#pragma unroll
    for (int j = 0; j < 4; ++j) acc[i][j] = (float4v){0.f, 0.f, 0.f, 0.f};

  for (int kc = 0; kc < 4; ++kc) {
    const int k0 = kc * 64;
    if (kc) __syncthreads();
    // A: 128 rows x 16 float4 k-cols, f32 -> f16
#pragma unroll
    for (int it = 0; it < 8; ++it) {
      int idx = it * 256 + tid;
      int row = idx >> 4, k4 = idx & 15;
      float4v v = *(const float4v*)(qf + (size_t)(blockM + row) * 256 + k0 + k4 * 4);
      half4 o;
      o[0] = (_Float16)v[0]; o[1] = (_Float16)v[1];
      o[2] = (_Float16)v[2]; o[3] = (_Float16)v[3];
      *(half4*)&As[row * LDSTR + k4 * 4] = o;
    }
    // B: 128 rows x 16 float4 k-cols from Wcat f32 (L2-resident, 394 KB)
#pragma unroll
    for (int it = 0; it < 8; ++it) {
      int idx = it * 256 + tid;
      int row = idx >> 4, k4 = idx & 15;
      int n = n0 + row;
      const float* src = (n < 256) ? (Woff + (size_t)n * 256)
                                   : (Wattn + (size_t)(n - 256) * 256);
      float4v v = *(const float4v*)(src + k0 + k4 * 4);
      half4 o;
      o[0] = (_Float16)v[0]; o[1] = (_Float16)v[1];
      o[2] = (_Float16)v[2]; o[3] = (_Float16)v[3];
      *(half4*)&Bs[row * LDSTR + k4 * 4] = o;
    }
    __syncthreads();

#pragma unroll
    for (int kf = 0; kf < 2; ++kf) {
      const int ko = kf * 32 + quad * 8;
      half8 af[4], bf[4];
#pragma unroll
      for (int mi = 0; mi < 4; ++mi)
        af[mi] = *(const half8*)&As[(wm * 64 + mi * 16 + r) * LDSTR + ko];
#pragma unroll
      for (int ni = 0; ni < 4; ++ni)
        bf[ni] = *(const half8*)&Bs[(wn * 64 + ni * 16 + r) * LDSTR + ko];
#pragma unroll
      for (int mi = 0; mi < 4; ++mi)
#pragma unroll
        for (int ni = 0; ni < 4; ++ni)
          acc[mi][ni] = __builtin_amdgcn_mfma_f32_16x16x32_f16(af[mi], bf[ni], acc[mi][ni], 0, 0, 0);
    }
  }

  // epilogue: n -> (head, slot): n<256: h=n>>5, slot=n&31 (offsets)
  //                              n>=256: h=(n-256)>>4, slot=32+((n-256)&15)
#pragma unroll
  for (int mi = 0; mi < 4; ++mi) {
    const int mb = blockM + wm * 64 + mi * 16 + quad * 4;
#pragma unroll
    for (int ni = 0; ni < 4; ++ni) {
      const int n = n0 + wn * 64 + ni * 16 + r;
      const float bias = (n < 256) ? boff[n] : battn[n - 256];
      const int h    = (n < 256) ? (n >> 5) : ((n - 256) >> 4);
      const int slot = (n < 256) ? (n & 31) : (32 + ((n - 256) & 15));
#pragma unroll
      for (int reg = 0; reg < 4; ++reg) {
        const int bq = mb + reg;
        const int b = bq >> 14, q = bq & 16383;
        lh[((size_t)(b * 8 + h) * NQ + q) * LREC + slot] =
            (_Float16)(acc[mi][ni][reg] + bias);
      }
    }
  }
}

// ---------------- K-S: sampling (level-split, 4 points per thread) ----------------
// grid 16384 flat; xcd = bid&7, local = bid>>3 (0..2047),
// hb = xcd*2 + (local>>10), qt = local&1023 -> 16 queries per block.
// thread: c4 = tid&3 (channels c4*8..+7), l = (tid>>2)&3 (level), qi = tid>>4.
// Quad (c4 0..3) of each (q,l) issues 4x16B adjacent per tap -> one 64B
// segment per instruction (R9 lesson preserved).
__global__ __launch_bounds__(256) void sample_kernel(
    const _Float16* __restrict__ vh, const float* __restrict__ refp,
    const _Float16* __restrict__ lh, float* __restrict__ out) {
  const int bid   = blockIdx.x;
  const int xcd   = bid & 7;
  const int local = bid >> 3;
  const int hb    = xcd * 2 + (local >> 10);  // 0..15, == b*8+h
  const int qt    = local & 1023;
  const int h     = hb & 7;
  const int b     = hb >> 3;
  const int tid = threadIdx.x;
  const int c4 = tid & 3;
  const int l  = (tid >> 2) & 3;
  const int qi = tid >> 4;                    // 0..15
  const int q  = qt * 16 + qi;
  const size_t bq = (size_t)b * NQ + q;
  const _Float16* rec = lh + ((size_t)hb * NQ + q) * LREC;

  // own level's 8 offsets (layout within record: l*8 + p*2 + xy)
  const half8 oh = *(const half8*)(rec + l * 8);
  // all 16 attn logits (for the softmax denominator)
  float al[16];
#pragma unroll
  for (int i = 0; i < 2; ++i) {
    half8 ah = *(const half8*)(rec + 32 + i * 8);
#pragma unroll
    for (int j = 0; j < 8; ++j) al[i * 8 + j] = (float)ah[j];
  }
  // own level's 4 logits as a separate aligned load (avoids runtime-indexed
  // al[] -> scratch, rule #20)
  const half4 ownl = *(const half4*)(rec + 32 + l * 4);

  float mx = -1e30f;
#pragma unroll
  for (int i = 0; i < 16; ++i) mx = fmaxf(mx, al[i]);
  float ssum = 0.f;
#pragma unroll
  for (int i = 0; i < 16; ++i) ssum += __expf(al[i] - mx);
  const float inv = 1.0f / ssum;

  float4v rp0 = *(const float4v*)(refp + bq * 8);
  float4v rp1 = *(const float4v*)(refp + bq * 8 + 4);
  const float rpx[4] = {rp0[0], rp0[2], rp1[0], rp1[2]};
  const float rpy[4] = {rp0[1], rp0[3], rp1[1], rp1[3]};

  // level geometry (runtime-uniform per thread; scalar values, no arrays)
  const int   W    = 128 >> l;
  const float fW   = (float)W;
  const int   base = (l == 0) ? 0 : (l == 1) ? 16384 : (l == 2) ? 20480 : 21504;
  const _Float16* vlev = vh + (size_t)b * NTOK * 256 + h * 32 + c4 * 8
                            + (size_t)base * 256;

  half2v accl0 = (half2v){(_Float16)0, (_Float16)0};
  half2v accl1 = (half2v){(_Float16)0, (_Float16)0};
  half2v accl2 = (half2v){(_Float16)0, (_Float16)0};
  half2v accl3 = (half2v){(_Float16)0, (_Float16)0};

#pragma unroll
  for (int p = 0; p < 4; ++p) {
    // a = softmax weight: exp(logit-mx) then *inv -- same ops as before
    const float a  = __expf((float)ownl[p] - mx) * inv;
    const float ox = (float)oh[p * 2];
    const float oy = (float)oh[p * 2 + 1];
    // (ref + off/shape)*2-1 through grid_sample == ref*W + off - 0.5
    const float x = rpx[p] * fW + ox - 0.5f;
    const float y = rpy[p] * fW + oy - 0.5f;
    const float xf = floorf(x), yf = floorf(y);
    const float fx = x - xf, fy = y - yf;
    const int ix = (int)xf, iy = (int)yf;
    const int ix0 = min(max(ix, 0), W - 1);
    const int ix1 = min(max(ix + 1, 0), W - 1);
    const int iy0 = min(max(iy, 0), W - 1);
    const int iy1 = min(max(iy + 1, 0), W - 1);
    const float wx0 = ((unsigned)ix       < (unsigned)W) ? 1.f - fx : 0.f;
    const float wx1 = ((unsigned)(ix + 1) < (unsigned)W) ? fx       : 0.f;
    const float wy0 = ((unsigned)iy       < (unsigned)W) ? 1.f - fy : 0.f;
    const float wy1 = ((unsigned)(iy + 1) < (unsigned)W) ? fy       : 0.f;
    const _Float16 w00 = (_Float16)(a * wx0 * wy0);
    const _Float16 w01 = (_Float16)(a * wx1 * wy0);
    const _Float16 w10 = (_Float16)(a * wx0 * wy1);
    const _Float16 w11 = (_Float16)(a * wx1 * wy1);
    const half2v h00 = (half2v){w00, w00};
    const half2v h01 = (half2v){w01, w01};
    const half2v h10 = (half2v){w10, w10};
    const half2v h11 = (half2v){w11, w11};
    const _Float16* r0 = vlev + (size_t)(iy0 * W) * 256;
    const _Float16* r1 = vlev + (size_t)(iy1 * W) * 256;
    H8 t00, t01, t10, t11;
    t00.v = *(const half8*)(r0 + ix0 * 256);
    t01.v = *(const half8*)(r0 + ix1 * 256);
    t10.v = *(const half8*)(r1 + ix0 * 256);
    t11.v = *(const half8*)(r1 + ix1 * 256);
    accl0 += h00 * t00.p[0] + h01 * t01.p[0] + h10 * t10.p[0] + h11 * t11.p[0];
    accl1 += h00 * t00.p[1] + h01 * t01.p[1] + h10 * t10.p[1] + h11 * t11.p[1];
    accl2 += h00 * t00.p[2] + h01 * t01.p[2] + h10 * t10.p[2] + h11 * t11.p[2];
    accl3 += h00 * t00.p[3] + h01 * t01.p[3] + h10 * t10.p[3] + h11 * t11.p[3];
  }

  // flush level accumulator to f32 (channels c4*8 .. c4*8+7)
  float acc0[4], acc1[4];
  acc0[0] = (float)accl0[0]; acc0[1] = (float)accl0[1];
  acc0[2] = (float)accl1[0]; acc0[3] = (float)accl1[1];
  acc1[0] = (float)accl2[0]; acc1[1] = (float)accl2[1];
  acc1[2] = (float)accl3[0]; acc1[3] = (float)accl3[1];

  // LDS cross-level reduce + transposed coalesced store.
  // sm[l][qi][c]: stride 33 floats -> write conflicts are 2-way max (free-ish).
  __shared__ float sm[4][16][33];
#pragma unroll
  for (int j = 0; j < 4; ++j) {
    sm[l][qi][c4 * 8 + j]     = acc0[j];
    sm[l][qi][c4 * 8 + 4 + j] = acc1[j];
  }
  __syncthreads();
  // 512 outputs (32c x 16q), 2 per thread; sum levels IN ORDER (numerics
  // identical to the old sequential per-level f32 accumulation).
  const size_t obase = ((size_t)b * 256 + h * 32) * NQ + qt * 16;
#pragma unroll
  for (int i = 0; i < 2; ++i) {
    const int idx = i * 256 + tid;
    const int c  = idx >> 4;
    const int ql = idx & 15;
    const float v = ((sm[0][ql][c] + sm[1][ql][c]) + sm[2][ql][c]) + sm[3][ql][c];
    out[obase + (size_t)c * NQ + ql] = v;
  }
}

extern "C" void kernel_launch(void* const* d_in, const int* in_sizes, int n_in,
                              void* d_out, int out_size, void* d_ws, size_t ws_size,
                              hipStream_t stream) {
  const float* query = (const float*)d_in[0];
  const float* value = (const float*)d_in[1];
  const float* refp  = (const float*)d_in[2];
  const float* Woff  = (const float*)d_in[3];
  const float* boff  = (const float*)d_in[4];
  const float* Wattn = (const float*)d_in[5];
  const float* battn = (const float*)d_in[6];
  float* out = (float*)d_out;

  char* ws = (char*)d_ws;
  _Float16* vh = (_Float16*)ws;                    // 22,282,240 B
  _Float16* lh = (_Float16*)(ws + 22282240);       // 25,165,824 B

  fused_kernel<<<GEMM_BLOCKS + CONV_BLOCKS, 256, 0, stream>>>(
      query, Woff, Wattn, boff, battn, value, lh, vh);
  sample_kernel<<<16384, 256, 0, stream>>>(vh, refp, lh, out);
}